// Round 16
// baseline (343.744 us; speedup 1.0000x reference)
//
#include <hip/hip_runtime.h>
#include <hip/hip_bf16.h>

typedef _Float16 v8h __attribute__((ext_vector_type(8)));
typedef _Float16 v4h __attribute__((ext_vector_type(4)));
typedef _Float16 v2h __attribute__((ext_vector_type(2)));
typedef float    v4f __attribute__((ext_vector_type(4)));
typedef int      v4i __attribute__((ext_vector_type(4)));
typedef int      v2i __attribute__((ext_vector_type(2)));

#define NTOT  16384
#define NN    70
#define STEPS 5
#define TPB   64                     // ONE wave per block; one graph per block
#define NBLK  NTOT
// r12 = verified best (195.5us): fused P3 (ds_bpermute rp exchange), pkrtz,
// separate P1/P2 phases. r13 lesson: fusing P1 into P3's tile loop deepens
// the serial chain and LOSES (195.5->212) -- keep phases separate.
// THIS ROUND: single variable = __launch_bounds__(64,3). Hypothesis: rocprof
// VGPR_Count(120) excludes AGPRs; gfx950's UNIFIED VGPR/AGPR file puts the
// true total in (170,256] -> HW caps 2 waves/SIMD = 8/CU = the ~7-wave
// invariant of r0-r12. min-waves=3 forces total <=170 -> 3 waves/SIMD.
#define CATN  40                     // cat node stride (r6-validated)
#define CATH  3208                   // 80 nodes * 40 + pad
#define USTR  232                    // U col stride (halves): 116 dw == 20 mod 32
#define UH    (10*USTR)              // 10 real cols; phantom-col B-frag reads
                                     // (c>=10) land in cat: finite, D rows
                                     // 10..15 discarded (r2/r3/r6-validated)

// epilogue weights (fp32, global scalar loads)
#define PWO1 0                       // 10 rows x 12: [Wo1[s][0..9], ann_coef, bo1[s]]
#define PWO2 120
#define PBO2 130
#define NWP  132

// fp16 fragment images (built by prep):
//  [0..1023]     P1 B-frags Wstack, 2 tiles:  nt*512 + lane*8 + j   (k<16 rows ZERO)
//  [1024..2047]  P3 A-frags Wr | Wz:          mt*512 + lane*8 + j
//  [2048..2559]  P3 A-frag  Wh:               lane*8 + j
//  [2560..20479] adjacency frags:             2560 + (mt*7+kt)*512 + lane*8 + j
//  NOTE: A-frag image of M == B-frag image of M^T for 16x16x32 (identical
//  (lane,j)->(row/col,k) map), so adjacency images serve as swapped-P2's B operand.
#define OFR  1024
#define OFZ  1536
#define OFH  2048
#define OFA  2560
#define NWF  20480
#define PREPB 40

__device__ __align__(16) float    g_w[NWP];
__device__ __align__(16) _Float16 g_wf[NWF];
__device__ int g_flag;

__device__ __forceinline__ float fast_sigmoid(float x) {
    return __builtin_amdgcn_rcpf(1.0f + __expf(-x));
}
__device__ __forceinline__ float fast_tanh(float x) {
    float ax = fabsf(x);
    float e  = __expf(-2.0f * ax);
    float t  = (1.0f - e) * __builtin_amdgcn_rcpf(1.0f + e);
    return copysignf(t, x);
}
// packed f32x2 -> f16x2 (v_cvt_pkrtz): RTZ on intermediates only; pn stays RNE.
__device__ __forceinline__ v4h pk4(v4f a) {
    auto lo = __builtin_amdgcn_cvt_pkrtz(a[0], a[1]);
    auto hi = __builtin_amdgcn_cvt_pkrtz(a[2], a[3]);
    v4h r; r[0] = lo[0]; r[1] = lo[1]; r[2] = hi[0]; r[3] = hi[1];
    return r;
}

struct __align__(16) Smem {
    _Float16 U[UH];      // 4640 B: U[col=s][k=e*72+node]
    _Float16 cat[CATH];  // 6416 B: cat[node][k]; k0..9=a_in, 16..25=prop, 26=1
};
// 11056 B -> 11264 alloc: LDS cap 14 blocks/CU (has never bound; reg total has)

// ---- prep: probe dtype; build epilogue weights + all fp16 fragment images ----
__global__ void prep_kernel(const void* annv, const void* Av,
    const void* winv, const void* binv, const void* wrv, const void* brv,
    const void* wzv, const void* bzv, const void* whv, const void* bhv,
    const void* wo1v, const void* bo1v, const void* wo2v, const void* bo2v)
{
    __shared__ int sflag;
    if (threadIdx.x == 0) {
        const unsigned short* u = (const unsigned short*)annv;
        int good = 0;
        for (int k = 0; k < 128; ++k) {
            unsigned short bb = u[k];
            int ex = (bb >> 7) & 0xFF;
            if (bb == 0 || (ex >= 101 && ex <= 131)) ++good;
        }
        sflag = (good >= 112) ? 1 : 0;
        if (blockIdx.x == 0) g_flag = sflag;
    }
    __syncthreads();
    const int f = sflag;
    #define RD(p, i) (f ? (float)((const __hip_bfloat16*)(p))[i] : ((const float*)(p))[i])
    const int tid = threadIdx.x;
    if (blockIdx.x == 0) {
        for (int idx = tid; idx < 120; idx += blockDim.x) {
            const int s = idx / 12, cc = idx - s*12;
            g_w[PWO1 + idx] = (cc < 11) ? RD(wo1v, s*11 + cc) : RD(bo1v, s);
        }
        for (int idx = tid; idx < 10; idx += blockDim.x) g_w[PWO2 + idx] = RD(wo2v, idx);
        if (tid == 0) { g_w[PBO2] = RD(bo2v, 0); g_w[PBO2+1] = 0.f; }
    }
    for (int idx = blockIdx.x*blockDim.x + tid; idx < NWF; idx += gridDim.x*blockDim.x) {
        float val = 0.f;
        if (idx < OFR) {
            // P1 B-frag: B[k][col=(e,s)]; k 16..25 -> Win[e][s][k-16], k 26 -> b_in
            const int nt = idx >> 9, rem = idx & 511, lane = rem >> 3, j = rem & 7;
            const int k = ((lane >> 4) << 3) + j, col = nt*16 + (lane & 15);
            if (col < 30) {
                const int e = col / 10, s = col - e*10;
                if (k >= 16 && k < 26) val = RD(winv, e*100 + s*10 + (k-16));
                else if (k == 26)      val = RD(binv, e*10 + s);
            }
        } else if (idx < OFH) {
            // P3 A-frags Wr/Wz: A[row=s][k]; k<10 -> W[s][k], 16..25 -> W[s][10+..], 26 -> bias
            const int i2 = idx - OFR;
            const int mt = i2 >> 9, rem = i2 & 511, lane = rem >> 3, j = rem & 7;
            const int k = ((lane >> 4) << 3) + j, s = lane & 15;
            if (s < 10) {
                const void* Wv = mt ? wzv : wrv;
                const void* bv = mt ? bzv : brv;
                if (k < 10)                 val = RD(Wv, s*20 + k);
                else if (k >= 16 && k < 26) val = RD(Wv, s*20 + 10 + (k-16));
                else if (k == 26)           val = RD(bv, s);
            }
        } else if (idx < OFA) {
            const int i2 = idx - OFH;
            const int lane = i2 >> 3, j = i2 & 7;
            const int k = ((lane >> 4) << 3) + j, s = lane & 15;
            if (s < 10) {
                if (k < 10)                 val = RD(whv, s*20 + k);
                else if (k >= 16 && k < 26) val = RD(whv, s*20 + 10 + (k-16));
                else if (k == 26)           val = RD(bhv, s);
            }
        } else {
            // adjacency frag: A[m=node][k=e*72+mm]; zero at pads
            const int i2 = idx - OFA;
            const int w = i2 / 3584, rem = i2 - w*3584;
            const int kt = rem >> 9, r2 = rem & 511, lane = r2 >> 3, j = r2 & 7;
            const int m = w*16 + (lane & 15);
            const int k = kt*32 + ((lane >> 4) << 3) + j;
            const int e = k / 72, mm = k - e*72;
            if (m < NN && e < 3 && mm < NN) val = RD(Av, m*210 + e*70 + mm);
        }
        g_wf[idx] = (_Float16)val;
    }
    #undef RD
}

template<typename T>
__device__ __forceinline__ void run_impl(const void* annv, void* outv, Smem& sm)
{
    const T* ann_g = (const T*)annv;
    T* out_g       = (T*)outv;
    const int lane = threadIdx.x;    // single wave
    const int blk  = blockIdx.x;     // == graph id
    const int q    = lane >> 4;
    const int c    = lane & 15;
    const float* __restrict__ gw = g_w;

    // ---- preload fragments as loop-hoisted arrays (r4/r6 winning schedule;
    //      compiler keeps what fits in the budget, batches reloads early)
    const v8h w1f0 = *(const v8h*)&g_wf[       lane*8];
    const v8h w1f1 = *(const v8h*)&g_wf[512  + lane*8];
    const v8h wrf  = *(const v8h*)&g_wf[OFR  + lane*8];
    const v8h wzf  = *(const v8h*)&g_wf[OFZ  + lane*8];
    const v8h whf  = *(const v8h*)&g_wf[OFH  + lane*8];
    v8h adj[35];
    #pragma unroll
    for (int i = 0; i < 35; ++i)
        adj[i] = *(const v8h*)&g_wf[OFA + i*512 + lane*8];

    // bpermute lane addresses for the P3 rp exchange (loop-invariant)
    const int a_lo  = c << 2;              // lane (0,c)
    const int a_mid = (16 + c) << 2;       // lane (1,c)
    const int a_sel = (q == 3) ? ((32 + c) << 2) : a_lo;   // q3 pulls from (2,c)

    // ---- zero LDS (phantom rows/cols MUST be zero)
    {
        const int4 zz = {0,0,0,0};
        int4* z = (int4*)&sm;
        #pragma unroll 4
        for (int i = lane; i < (int)(sizeof(Smem)/16); i += TPB) z[i] = zz;
    }
    __syncthreads();

    // ---- seed: prop[0]=ann at k=16, bias-one at k=26
    for (int n2 = lane; n2 < NN; n2 += TPB) {
        sm.cat[n2*CATN + 16] = (_Float16)(float)ann_g[blk*NN + n2];
        sm.cat[n2*CATN + 26] = (_Float16)1.0f;
    }
    __syncthreads();

    // ---- P1: ins(prop) -> U   (A=cat rows, B=Wstack frags)
    #define PHASE1() do {                                                        \
        _Pragma("unroll")                                                        \
        for (int mt = 0; mt < 5; ++mt) {                                         \
            const v8h af = *(const v8h*)&sm.cat[(mt*16 + c)*CATN + q*8];         \
            const int node0 = mt*16 + q*4;                                       \
            _Pragma("unroll")                                                    \
            for (int nt = 0; nt < 2; ++nt) {                                     \
                v4f acc = {0.f,0.f,0.f,0.f};                                     \
                acc = __builtin_amdgcn_mfma_f32_16x16x32_f16(                    \
                        af, nt ? w1f1 : w1f0, acc, 0,0,0);                       \
                const int colw = nt*16 + c;                                      \
                if (colw < 30 && node0 <= 68) {                                  \
                    const int e = colw / 10, s = colw - e*10;                    \
                    *(v4h*)&sm.U[s*USTR + e*72 + node0] = pk4(acc);              \
                }                                                                \
            }                                                                    \
        }                                                                        \
    } while(0)

    PHASE1();
    __syncthreads();

    #pragma unroll 1
    for (int step = 0; step < STEPS; ++step) {
        // ---- P2 (operand-swapped): a_in^T = U-frag (A) x adj-frag (B)
        {
            v8h bfr[7];
            #pragma unroll
            for (int kt = 0; kt < 7; ++kt)
                bfr[kt] = *(const v8h*)&sm.U[c*USTR + q*8 + kt*32];
            #pragma unroll
            for (int mt = 0; mt < 5; ++mt) {
                v4f acc = {0.f,0.f,0.f,0.f};
                #pragma unroll
                for (int kt = 0; kt < 7; ++kt)
                    acc = __builtin_amdgcn_mfma_f32_16x16x32_f16(
                        bfr[kt], adj[mt*7+kt], acc, 0,0,0);
                const int node = mt*16 + c;
                if (node < NN) {
                    const v4h hv = pk4(acc);
                    _Float16* wp = &sm.cat[node*CATN + q*4];   // s = q*4..q*4+3
                    if (q < 2)       *(v4h*)wp = hv;
                    else if (q == 2) *(v2h*)wp = (v2h){hv[0], hv[1]};   // s=8,9
                }
            }
        }
        __syncthreads();   // a_in visible

        // ---- P3 FUSED per node-tile (r12-validated): r,z gates -> rp via
        //      ds_bpermute (in-register) -> h gate -> state update.
        {
            #pragma unroll
            for (int nt = 0; nt < 5; ++nt) {
                const int node = nt*16 + c;
                const v8h bf = *(const v8h*)&sm.cat[node*CATN + q*8];
                v4f ar = {0.f,0.f,0.f,0.f}, az = {0.f,0.f,0.f,0.f};
                ar = __builtin_amdgcn_mfma_f32_16x16x32_f16(wrf, bf, ar, 0,0,0);
                az = __builtin_amdgcn_mfma_f32_16x16x32_f16(wzf, bf, az, 0,0,0);
                const v4h pv = *(const v4h*)&sm.cat[node*CATN + 16 + q*4];
                float pg[4], zg[4];
                v4f rpf;
                #pragma unroll
                for (int i = 0; i < 4; ++i) {
                    pg[i]  = (float)pv[i];
                    zg[i]  = fast_sigmoid(az[i]);
                    rpf[i] = fast_sigmoid(ar[i]) * pg[i];
                }
                const v4h rp = pk4(rpf);
                const v2i rpi = __builtin_bit_cast(v2i, rp);
                const int d0 = __builtin_amdgcn_ds_bpermute(a_sel, rpi[0]);
                const int d1 = __builtin_amdgcn_ds_bpermute(a_lo,  rpi[1]);
                const int d2 = __builtin_amdgcn_ds_bpermute(a_mid, rpi[0]);
                const int d3 = __builtin_amdgcn_ds_bpermute(a_mid, rpi[1]);
                const v4i bfi = __builtin_bit_cast(v4i, bf);
                v4i b2;
                b2[0] = (q < 2) ? bfi[0] : d0;
                b2[1] = (q < 2) ? bfi[1] : ((q == 2) ? d1 : 0x00003C00); // k26=1
                b2[2] = (q < 2) ? bfi[2] : ((q == 2) ? d2 : 0);
                b2[3] = (q < 2) ? bfi[3] : ((q == 2) ? d3 : 0);
                const v8h bf2 = __builtin_bit_cast(v8h, b2);
                v4f ah = {0.f,0.f,0.f,0.f};
                ah = __builtin_amdgcn_mfma_f32_16x16x32_f16(whf, bf2, ah, 0,0,0);
                v4h pn;
                #pragma unroll
                for (int i = 0; i < 4; ++i) {
                    const float hh = fast_tanh(ah[i]);
                    pn[i] = (_Float16)(pg[i] + zg[i]*(hh - pg[i]));  // RNE state
                }
                if (node < NN) {
                    _Float16* wp = &sm.cat[node*CATN + 16 + q*4];
                    if (q < 2)       *(v4h*)wp = pn;
                    else if (q == 2) *(v2h*)wp = (v2h){pn[0], pn[1]};
                }
            }
        }
        __syncthreads();   // new prop visible (cross-q for P1's reads)

        // ---- P1 for next step (separate phase: inter-tile MFMA ILP — r13
        //      proved fusing this into P3's loop serializes and loses)
        if (step < STEPS-1) {
            PHASE1();
            __syncthreads();
        }
    }
    #undef PHASE1

    // ---- epilogue: one output per node
    for (int n2 = lane; n2 < NN; n2 += TPB) {
        const _Float16* pc = &sm.cat[n2*CATN + 16];
        const v8h p8 = *(const v8h*)pc;
        const v2h p2 = *(const v2h*)(pc + 8);
        float pr[10];
        #pragma unroll
        for (int i = 0; i < 8; ++i) pr[i] = (float)p8[i];
        pr[8] = (float)p2[0]; pr[9] = (float)p2[1];
        const float av = (float)ann_g[blk*NN + n2];
        float o = gw[PBO2];
        #pragma unroll
        for (int s = 0; s < 10; ++s) {
            const float* wr_ = &gw[PWO1 + s*12];
            float acc = wr_[11] + wr_[10]*av;
            #pragma unroll
            for (int d = 0; d < 10; ++d) acc += pr[d]*wr_[d];
            o += fast_tanh(acc) * gw[PWO2 + s];
        }
        out_g[blk*NN + n2] = (T)o;
    }
}

// __launch_bounds__(64,3): force TOTAL (VGPR+AGPR, unified file) <= ~170 so
// 3 waves/SIMD fit. Hypothesis: r0-r12's stubborn ~7 waves/CU = 2/SIMD cap
// from unified-file total in (170,256] (rocprof VGPR_Count excludes AGPRs).
// Tripwires: WRITE_SIZE >> 4.9MB => squeezed-spill (r1 mode) => revert to
// (64,2); occupancy still ~22% => hypothesis dead, r12 is the floor.
__global__ __launch_bounds__(TPB, 3)
void ggnn_kernel(const void* annv, void* outv)
{
    __shared__ Smem sm;
    if (g_flag)
        run_impl<__hip_bfloat16>(annv, outv, sm);
    else
        run_impl<float>(annv, outv, sm);
}

extern "C" void kernel_launch(void* const* d_in, const int* in_sizes, int n_in,
                              void* d_out, int out_size, void* d_ws, size_t ws_size,
                              hipStream_t stream) {
    (void)in_sizes; (void)n_in; (void)out_size; (void)d_ws; (void)ws_size;
    hipLaunchKernelGGL(prep_kernel, dim3(PREPB), dim3(256), 0, stream,
        d_in[0], d_in[1], d_in[2], d_in[3], d_in[4], d_in[5], d_in[6],
        d_in[7], d_in[8], d_in[9], d_in[10], d_in[11], d_in[12], d_in[13]);
    hipLaunchKernelGGL(ggnn_kernel, dim3(NBLK), dim3(TPB), 0, stream,
        d_in[0], d_out);
}

// Round 19
// 258.859 us; speedup vs baseline: 1.3279x; 1.3279x over previous
//
#include <hip/hip_runtime.h>
#include <hip/hip_bf16.h>

typedef _Float16 v8h __attribute__((ext_vector_type(8)));
typedef _Float16 v4h __attribute__((ext_vector_type(4)));
typedef _Float16 v2h __attribute__((ext_vector_type(2)));
typedef float    v4f __attribute__((ext_vector_type(4)));
typedef int      v4i __attribute__((ext_vector_type(4)));
typedef int      v2i __attribute__((ext_vector_type(2)));

#define NTOT  16384
#define NN    70
#define STEPS 5
#define TPB   64                     // ONE wave per block; one graph per block
#define NBLK  NTOT
// r12 = verified best (195.5us). r16 closed the occupancy lever: min-waves=3
// squeezed to 84 VGPR and spilled 210MB (occupancy 32% but dur 275) --
// registers ARE the occupancy limiter (unified VGPR/AGPR file) AND the live
// set needs the 2-wave tier. Seven occupancy experiments all lost.
// THIS ROUND: r12 + s_setprio(1) around MFMA clusters (T5). Our regime ==
// m191's attn case (independent 1-wave blocks at different phases, +4-7%),
// NOT m190's null (barrier-locked multi-wave). Zero-risk add-on.
#define CATN  40                     // cat node stride (r6-validated)
#define CATH  3208                   // 80 nodes * 40 + pad
#define USTR  232                    // U col stride (halves): 116 dw == 20 mod 32
#define UH    (10*USTR)              // 10 real cols; phantom-col B-frag reads
                                     // (c>=10) land in cat: finite, D rows
                                     // 10..15 discarded (r2/r3/r6-validated)

// epilogue weights (fp32, global scalar loads)
#define PWO1 0                       // 10 rows x 12: [Wo1[s][0..9], ann_coef, bo1[s]]
#define PWO2 120
#define PBO2 130
#define NWP  132

// fp16 fragment images (built by prep):
//  [0..1023]     P1 B-frags Wstack, 2 tiles:  nt*512 + lane*8 + j   (k<16 rows ZERO)
//  [1024..2047]  P3 A-frags Wr | Wz:          mt*512 + lane*8 + j
//  [2048..2559]  P3 A-frag  Wh:               lane*8 + j
//  [2560..20479] adjacency frags:             2560 + (mt*7+kt)*512 + lane*8 + j
//  NOTE: A-frag image of M == B-frag image of M^T for 16x16x32 (identical
//  (lane,j)->(row/col,k) map), so adjacency images serve as swapped-P2's B operand.
#define OFR  1024
#define OFZ  1536
#define OFH  2048
#define OFA  2560
#define NWF  20480
#define PREPB 40

__device__ __align__(16) float    g_w[NWP];
__device__ __align__(16) _Float16 g_wf[NWF];
__device__ int g_flag;

__device__ __forceinline__ float fast_sigmoid(float x) {
    return __builtin_amdgcn_rcpf(1.0f + __expf(-x));
}
__device__ __forceinline__ float fast_tanh(float x) {
    float ax = fabsf(x);
    float e  = __expf(-2.0f * ax);
    float t  = (1.0f - e) * __builtin_amdgcn_rcpf(1.0f + e);
    return copysignf(t, x);
}
// packed f32x2 -> f16x2 (v_cvt_pkrtz): RTZ on intermediates only; pn stays RNE.
__device__ __forceinline__ v4h pk4(v4f a) {
    auto lo = __builtin_amdgcn_cvt_pkrtz(a[0], a[1]);
    auto hi = __builtin_amdgcn_cvt_pkrtz(a[2], a[3]);
    v4h r; r[0] = lo[0]; r[1] = lo[1]; r[2] = hi[0]; r[3] = hi[1];
    return r;
}

struct __align__(16) Smem {
    _Float16 U[UH];      // 4640 B: U[col=s][k=e*72+node]
    _Float16 cat[CATH];  // 6416 B: cat[node][k]; k0..9=a_in, 16..25=prop, 26=1
};
// 11056 B -> 11264 alloc

// ---- prep: probe dtype; build epilogue weights + all fp16 fragment images ----
__global__ void prep_kernel(const void* annv, const void* Av,
    const void* winv, const void* binv, const void* wrv, const void* brv,
    const void* wzv, const void* bzv, const void* whv, const void* bhv,
    const void* wo1v, const void* bo1v, const void* wo2v, const void* bo2v)
{
    __shared__ int sflag;
    if (threadIdx.x == 0) {
        const unsigned short* u = (const unsigned short*)annv;
        int good = 0;
        for (int k = 0; k < 128; ++k) {
            unsigned short bb = u[k];
            int ex = (bb >> 7) & 0xFF;
            if (bb == 0 || (ex >= 101 && ex <= 131)) ++good;
        }
        sflag = (good >= 112) ? 1 : 0;
        if (blockIdx.x == 0) g_flag = sflag;
    }
    __syncthreads();
    const int f = sflag;
    #define RD(p, i) (f ? (float)((const __hip_bfloat16*)(p))[i] : ((const float*)(p))[i])
    const int tid = threadIdx.x;
    if (blockIdx.x == 0) {
        for (int idx = tid; idx < 120; idx += blockDim.x) {
            const int s = idx / 12, cc = idx - s*12;
            g_w[PWO1 + idx] = (cc < 11) ? RD(wo1v, s*11 + cc) : RD(bo1v, s);
        }
        for (int idx = tid; idx < 10; idx += blockDim.x) g_w[PWO2 + idx] = RD(wo2v, idx);
        if (tid == 0) { g_w[PBO2] = RD(bo2v, 0); g_w[PBO2+1] = 0.f; }
    }
    for (int idx = blockIdx.x*blockDim.x + tid; idx < NWF; idx += gridDim.x*blockDim.x) {
        float val = 0.f;
        if (idx < OFR) {
            // P1 B-frag: B[k][col=(e,s)]; k 16..25 -> Win[e][s][k-16], k 26 -> b_in
            const int nt = idx >> 9, rem = idx & 511, lane = rem >> 3, j = rem & 7;
            const int k = ((lane >> 4) << 3) + j, col = nt*16 + (lane & 15);
            if (col < 30) {
                const int e = col / 10, s = col - e*10;
                if (k >= 16 && k < 26) val = RD(winv, e*100 + s*10 + (k-16));
                else if (k == 26)      val = RD(binv, e*10 + s);
            }
        } else if (idx < OFH) {
            // P3 A-frags Wr/Wz: A[row=s][k]; k<10 -> W[s][k], 16..25 -> W[s][10+..], 26 -> bias
            const int i2 = idx - OFR;
            const int mt = i2 >> 9, rem = i2 & 511, lane = rem >> 3, j = rem & 7;
            const int k = ((lane >> 4) << 3) + j, s = lane & 15;
            if (s < 10) {
                const void* Wv = mt ? wzv : wrv;
                const void* bv = mt ? bzv : brv;
                if (k < 10)                 val = RD(Wv, s*20 + k);
                else if (k >= 16 && k < 26) val = RD(Wv, s*20 + 10 + (k-16));
                else if (k == 26)           val = RD(bv, s);
            }
        } else if (idx < OFA) {
            const int i2 = idx - OFH;
            const int lane = i2 >> 3, j = i2 & 7;
            const int k = ((lane >> 4) << 3) + j, s = lane & 15;
            if (s < 10) {
                if (k < 10)                 val = RD(whv, s*20 + k);
                else if (k >= 16 && k < 26) val = RD(whv, s*20 + 10 + (k-16));
                else if (k == 26)           val = RD(bhv, s);
            }
        } else {
            // adjacency frag: A[m=node][k=e*72+mm]; zero at pads
            const int i2 = idx - OFA;
            const int w = i2 / 3584, rem = i2 - w*3584;
            const int kt = rem >> 9, r2 = rem & 511, lane = r2 >> 3, j = r2 & 7;
            const int m = w*16 + (lane & 15);
            const int k = kt*32 + ((lane >> 4) << 3) + j;
            const int e = k / 72, mm = k - e*72;
            if (m < NN && e < 3 && mm < NN) val = RD(Av, m*210 + e*70 + mm);
        }
        g_wf[idx] = (_Float16)val;
    }
    #undef RD
}

template<typename T>
__device__ __forceinline__ void run_impl(const void* annv, void* outv, Smem& sm)
{
    const T* ann_g = (const T*)annv;
    T* out_g       = (T*)outv;
    const int lane = threadIdx.x;    // single wave
    const int blk  = blockIdx.x;     // == graph id
    const int q    = lane >> 4;
    const int c    = lane & 15;
    const float* __restrict__ gw = g_w;

    // ---- preload fragments as loop-hoisted arrays (r4/r6 winning schedule;
    //      compiler keeps what fits in the budget, batches reloads early)
    const v8h w1f0 = *(const v8h*)&g_wf[       lane*8];
    const v8h w1f1 = *(const v8h*)&g_wf[512  + lane*8];
    const v8h wrf  = *(const v8h*)&g_wf[OFR  + lane*8];
    const v8h wzf  = *(const v8h*)&g_wf[OFZ  + lane*8];
    const v8h whf  = *(const v8h*)&g_wf[OFH  + lane*8];
    v8h adj[35];
    #pragma unroll
    for (int i = 0; i < 35; ++i)
        adj[i] = *(const v8h*)&g_wf[OFA + i*512 + lane*8];

    // bpermute lane addresses for the P3 rp exchange (loop-invariant)
    const int a_lo  = c << 2;              // lane (0,c)
    const int a_mid = (16 + c) << 2;       // lane (1,c)
    const int a_sel = (q == 3) ? ((32 + c) << 2) : a_lo;   // q3 pulls from (2,c)

    // ---- zero LDS (phantom rows/cols MUST be zero)
    {
        const int4 zz = {0,0,0,0};
        int4* z = (int4*)&sm;
        #pragma unroll 4
        for (int i = lane; i < (int)(sizeof(Smem)/16); i += TPB) z[i] = zz;
    }
    __syncthreads();

    // ---- seed: prop[0]=ann at k=16, bias-one at k=26
    for (int n2 = lane; n2 < NN; n2 += TPB) {
        sm.cat[n2*CATN + 16] = (_Float16)(float)ann_g[blk*NN + n2];
        sm.cat[n2*CATN + 26] = (_Float16)1.0f;
    }
    __syncthreads();

    // ---- P1: ins(prop) -> U   (A=cat rows, B=Wstack frags)
    //      setprio(1) over the MFMA cluster: independent 1-wave blocks at
    //      different phases -> scheduler prefers the MFMA-feeding wave (T5/m191)
    #define PHASE1() do {                                                        \
        __builtin_amdgcn_s_setprio(1);                                           \
        _Pragma("unroll")                                                        \
        for (int mt = 0; mt < 5; ++mt) {                                         \
            const v8h af = *(const v8h*)&sm.cat[(mt*16 + c)*CATN + q*8];         \
            const int node0 = mt*16 + q*4;                                       \
            _Pragma("unroll")                                                    \
            for (int nt = 0; nt < 2; ++nt) {                                     \
                v4f acc = {0.f,0.f,0.f,0.f};                                     \
                acc = __builtin_amdgcn_mfma_f32_16x16x32_f16(                    \
                        af, nt ? w1f1 : w1f0, acc, 0,0,0);                       \
                const int colw = nt*16 + c;                                      \
                if (colw < 30 && node0 <= 68) {                                  \
                    const int e = colw / 10, s = colw - e*10;                    \
                    *(v4h*)&sm.U[s*USTR + e*72 + node0] = pk4(acc);              \
                }                                                                \
            }                                                                    \
        }                                                                        \
        __builtin_amdgcn_s_setprio(0);                                           \
    } while(0)

    PHASE1();
    __syncthreads();

    #pragma unroll 1
    for (int step = 0; step < STEPS; ++step) {
        // ---- P2 (operand-swapped): a_in^T = U-frag (A) x adj-frag (B)
        {
            v8h bfr[7];
            #pragma unroll
            for (int kt = 0; kt < 7; ++kt)
                bfr[kt] = *(const v8h*)&sm.U[c*USTR + q*8 + kt*32];
            __builtin_amdgcn_s_setprio(1);
            #pragma unroll
            for (int mt = 0; mt < 5; ++mt) {
                v4f acc = {0.f,0.f,0.f,0.f};
                #pragma unroll
                for (int kt = 0; kt < 7; ++kt)
                    acc = __builtin_amdgcn_mfma_f32_16x16x32_f16(
                        bfr[kt], adj[mt*7+kt], acc, 0,0,0);
                const int node = mt*16 + c;
                if (node < NN) {
                    const v4h hv = pk4(acc);
                    _Float16* wp = &sm.cat[node*CATN + q*4];   // s = q*4..q*4+3
                    if (q < 2)       *(v4h*)wp = hv;
                    else if (q == 2) *(v2h*)wp = (v2h){hv[0], hv[1]};   // s=8,9
                }
            }
            __builtin_amdgcn_s_setprio(0);
        }
        __syncthreads();   // a_in visible

        // ---- P3 FUSED per node-tile (r12-validated): r,z gates -> rp via
        //      ds_bpermute (in-register) -> h gate -> state update.
        //      setprio raised only over the MFMA pairs, dropped for gate VALU.
        {
            #pragma unroll
            for (int nt = 0; nt < 5; ++nt) {
                const int node = nt*16 + c;
                const v8h bf = *(const v8h*)&sm.cat[node*CATN + q*8];
                v4f ar = {0.f,0.f,0.f,0.f}, az = {0.f,0.f,0.f,0.f};
                __builtin_amdgcn_s_setprio(1);
                ar = __builtin_amdgcn_mfma_f32_16x16x32_f16(wrf, bf, ar, 0,0,0);
                az = __builtin_amdgcn_mfma_f32_16x16x32_f16(wzf, bf, az, 0,0,0);
                __builtin_amdgcn_s_setprio(0);
                const v4h pv = *(const v4h*)&sm.cat[node*CATN + 16 + q*4];
                float pg[4], zg[4];
                v4f rpf;
                #pragma unroll
                for (int i = 0; i < 4; ++i) {
                    pg[i]  = (float)pv[i];
                    zg[i]  = fast_sigmoid(az[i]);
                    rpf[i] = fast_sigmoid(ar[i]) * pg[i];
                }
                const v4h rp = pk4(rpf);
                const v2i rpi = __builtin_bit_cast(v2i, rp);
                const int d0 = __builtin_amdgcn_ds_bpermute(a_sel, rpi[0]);
                const int d1 = __builtin_amdgcn_ds_bpermute(a_lo,  rpi[1]);
                const int d2 = __builtin_amdgcn_ds_bpermute(a_mid, rpi[0]);
                const int d3 = __builtin_amdgcn_ds_bpermute(a_mid, rpi[1]);
                const v4i bfi = __builtin_bit_cast(v4i, bf);
                v4i b2;
                b2[0] = (q < 2) ? bfi[0] : d0;
                b2[1] = (q < 2) ? bfi[1] : ((q == 2) ? d1 : 0x00003C00); // k26=1
                b2[2] = (q < 2) ? bfi[2] : ((q == 2) ? d2 : 0);
                b2[3] = (q < 2) ? bfi[3] : ((q == 2) ? d3 : 0);
                const v8h bf2 = __builtin_bit_cast(v8h, b2);
                v4f ah = {0.f,0.f,0.f,0.f};
                __builtin_amdgcn_s_setprio(1);
                ah = __builtin_amdgcn_mfma_f32_16x16x32_f16(whf, bf2, ah, 0,0,0);
                __builtin_amdgcn_s_setprio(0);
                v4h pn;
                #pragma unroll
                for (int i = 0; i < 4; ++i) {
                    const float hh = fast_tanh(ah[i]);
                    pn[i] = (_Float16)(pg[i] + zg[i]*(hh - pg[i]));  // RNE state
                }
                if (node < NN) {
                    _Float16* wp = &sm.cat[node*CATN + 16 + q*4];
                    if (q < 2)       *(v4h*)wp = pn;
                    else if (q == 2) *(v2h*)wp = (v2h){pn[0], pn[1]};
                }
            }
        }
        __syncthreads();   // new prop visible (cross-q for P1's reads)

        // ---- P1 for next step (separate phase: inter-tile MFMA ILP — r13
        //      proved fusing this into P3's loop serializes and loses)
        if (step < STEPS-1) {
            PHASE1();
            __syncthreads();
        }
    }
    #undef PHASE1

    // ---- epilogue: one output per node
    for (int n2 = lane; n2 < NN; n2 += TPB) {
        const _Float16* pc = &sm.cat[n2*CATN + 16];
        const v8h p8 = *(const v8h*)pc;
        const v2h p2 = *(const v2h*)(pc + 8);
        float pr[10];
        #pragma unroll
        for (int i = 0; i < 8; ++i) pr[i] = (float)p8[i];
        pr[8] = (float)p2[0]; pr[9] = (float)p2[1];
        const float av = (float)ann_g[blk*NN + n2];
        float o = gw[PBO2];
        #pragma unroll
        for (int s = 0; s < 10; ++s) {
            const float* wr_ = &gw[PWO1 + s*12];
            float acc = wr_[11] + wr_[10]*av;
            #pragma unroll
            for (int d = 0; d < 10; ++d) acc += pr[d]*wr_[d];
            o += fast_tanh(acc) * gw[PWO2 + s];
        }
        out_g[blk*NN + n2] = (T)o;
    }
}

// __launch_bounds__(64,2): the ONLY viable register tier (r16: min=3 squeezes
// to 84 VGPR and spills 210MB; r1: min=4 same at 64). 120 VGPR, no spill.
// Tripwire: WRITE_SIZE >> 4.9MB => spill => revert.
__global__ __launch_bounds__(TPB, 2)
void ggnn_kernel(const void* annv, void* outv)
{
    __shared__ Smem sm;
    if (g_flag)
        run_impl<__hip_bfloat16>(annv, outv, sm);
    else
        run_impl<float>(annv, outv, sm);
}

extern "C" void kernel_launch(void* const* d_in, const int* in_sizes, int n_in,
                              void* d_out, int out_size, void* d_ws, size_t ws_size,
                              hipStream_t stream) {
    (void)in_sizes; (void)n_in; (void)out_size; (void)d_ws; (void)ws_size;
    hipLaunchKernelGGL(prep_kernel, dim3(PREPB), dim3(256), 0, stream,
        d_in[0], d_in[1], d_in[2], d_in[3], d_in[4], d_in[5], d_in[6],
        d_in[7], d_in[8], d_in[9], d_in[10], d_in[11], d_in[12], d_in[13]);
    hipLaunchKernelGGL(ggnn_kernel, dim3(NBLK), dim3(TPB), 0, stream,
        d_in[0], d_out);
}